// Round 20
// baseline (175.950 us; speedup 1.0000x reference)
//
#include <hip/hip_runtime.h>
#include <math.h>

#define B_ 64
#define Q_ 900
#define C_ 256
#define T_ 100
#define N_ 100            // min(Q,T)
#define BIGF 1.0e30f
#define ROWS_PER_LANE 15  // ceil(900/64) — rescan striding
#define CHUNKS 25         // row-chunks for colmin partials
#define RPC 36            // rows per chunk

typedef unsigned int u32;
typedef unsigned long long ull;

// ---------------------------------------------------------------------------
// Key scheme:
//   u64 key  = ordf(v)<<18 | stale<<17 | row<<7 | t   (partials / rescan)
//   ikey = ~key (max semantics, identity 0)
// Greedy holds 32-bit split state: v = ordf(val), id = stale<<17|row<<7|t.
// Pick order = lex(value, stale, row, t) == jnp.argmin flat order for fresh.
// ---------------------------------------------------------------------------
__device__ inline u32 hm_ordf(float v) {
    u32 u = __float_as_uint(v);
    return (u & 0x80000000u) ? ~u : (u | 0x80000000u);
}
__device__ inline ull hm_ikey(float v, int r, int t) {
    return ~(((ull)hm_ordf(v) << 18) | ((ull)(u32)r << 7) | (ull)(u32)t);
}

// ---------------------------------------------------------------------------
// DPP helpers.
// ---------------------------------------------------------------------------
__device__ inline u32 hm_umax32(u32 a, u32 b) { return a > b ? a : b; }

__device__ inline u32 hm_wave_max_u32_full(u32 y) {
    y = hm_umax32(y, (u32)__builtin_amdgcn_update_dpp(0, (int)y, 0x111, 0xF, 0xF, false));
    y = hm_umax32(y, (u32)__builtin_amdgcn_update_dpp(0, (int)y, 0x112, 0xF, 0xF, false));
    y = hm_umax32(y, (u32)__builtin_amdgcn_update_dpp(0, (int)y, 0x114, 0xF, 0xF, false));
    y = hm_umax32(y, (u32)__builtin_amdgcn_update_dpp(0, (int)y, 0x118, 0xF, 0xF, false));
    y = hm_umax32(y, (u32)__builtin_amdgcn_update_dpp(0, (int)y, 0x142, 0xF, 0xF, false));
    y = hm_umax32(y, (u32)__builtin_amdgcn_update_dpp(0, (int)y, 0x143, 0xF, 0xF, false));
    return (u32)__builtin_amdgcn_readlane((int)y, 63);
}

template <int CTRL>
__device__ inline ull hm_dpp64(ull x) {
    u32 lo = (u32)x, hi = (u32)(x >> 32);
    lo = (u32)__builtin_amdgcn_update_dpp(0, (int)lo, CTRL, 0xF, 0xF, false);
    hi = (u32)__builtin_amdgcn_update_dpp(0, (int)hi, CTRL, 0xF, 0xF, false);
    return ((ull)hi << 32) | lo;
}
__device__ inline ull hm_wave_max_full64(ull x) {     // rare rescan path only
    ull p;
    p = hm_dpp64<0x111>(x); x = (p > x) ? p : x;
    p = hm_dpp64<0x112>(x); x = (p > x) ? p : x;
    p = hm_dpp64<0x114>(x); x = (p > x) ? p : x;
    p = hm_dpp64<0x118>(x); x = (p > x) ? p : x;
    p = hm_dpp64<0x142>(x); x = (p > x) ? p : x;
    p = hm_dpp64<0x143>(x); x = (p > x) ? p : x;
    u32 lo = (u32)__builtin_amdgcn_readlane((int)(u32)x, 63);
    u32 hi = (u32)__builtin_amdgcn_readlane((int)(u32)(x >> 32), 63);
    return ((ull)hi << 32) | lo;
}

// ---------------------------------------------------------------------------
// Counter zeroing (runs before the fused kernel each launch; replay-safe).
// ---------------------------------------------------------------------------
__global__ void hm_zero(int* __restrict__ cnt) {
    if (threadIdx.x < B_) cnt[threadIdx.x] = 0;
}

// ---------------------------------------------------------------------------
// FUSED kernel: blocks 0..B_*CHUNKS-1 = cost+colmin producers (R18's verbatim
// 4-wave f32 body, measured 34.7 us); blocks B_*CHUNKS.. = per-batch greedy
// consumers (R18's verbatim two-phase DPP body, measured 54.5 us) that
// spin-wait on the per-batch completion counter, then run.
// Producer/consumer protocol: producers __syncthreads + single-thread
// __threadfence + device-scope atomicAdd(RELEASE); consumers spin on
// __hip_atomic_load(ACQUIRE, AGENT) (invalidates stale L2 across replays).
// Wait graph is acyclic (producers never wait) -> no deadlock; 64 spinning
// waves can't starve producer scheduling (8192 wave slots on device).
// ---------------------------------------------------------------------------
__global__ __launch_bounds__(256) void hm_fused(
    const float* __restrict__ logits,   // [B,Q,C]
    const float* __restrict__ pboxes,   // [B,Q,4] cxcywh
    const int*   __restrict__ tlabels,  // [B,T]
    const float* __restrict__ tboxes,   // [B,T,4] cxcywh
    float* __restrict__ cost,           // [B,Q,T]
    ull* __restrict__ part,             // [B,CHUNKS,T,2] inverted top-2 keys
    int* __restrict__ cnt,              // [B] completion counters
    float* __restrict__ out_src,        // [B,N]
    float* __restrict__ out_tgt)        // [B,N]
{
    int bc = blockIdx.x;

    if (bc < B_ * CHUNKS) {
        // =================== PRODUCER: cost + colmin chunk ===================
        int b    = bc / CHUNKS;
        int c    = bc % CHUNKS;
        int lane = threadIdx.x & 63;
        int wid  = threadIdx.x >> 6;        // 0..3
        int r0   = c * RPC;

        __shared__ float s_exp[4][C_];      // 4 KB
        __shared__ ull   s_part[4][128][2]; // 8 KB

        int ta = lane, tb = 64 + lane;
        bool hb = (tb < T_);
        int laba = tlabels[b * T_ + ta];
        int labb = hb ? tlabels[b * T_ + tb] : 0;
        const float* tba = tboxes + ((size_t)b * T_ + ta) * 4;
        const float* tbb = tboxes + ((size_t)b * T_ + (hb ? tb : 0)) * 4;
        float tcxa = tba[0], tcya = tba[1], twa = tba[2], tha = tba[3];
        float tcxb = tbb[0], tcyb = tbb[1], twb = tbb[2], thb_ = tbb[3];
        float txa1 = tcxa - 0.5f * twa, tya1 = tcya - 0.5f * tha;
        float txa2 = tcxa + 0.5f * twa, tya2 = tcya + 0.5f * tha;
        float txb1 = tcxb - 0.5f * twb, tyb1 = tcyb - 0.5f * thb_;
        float txb2 = tcxb + 0.5f * twb, tyb2 = tcyb + 0.5f * thb_;
        float area2a = fmaxf(txa2 - txa1, 0.0f) * fmaxf(tya2 - tya1, 0.0f);
        float area2b = fmaxf(txb2 - txb1, 0.0f) * fmaxf(tyb2 - tyb1, 0.0f);

        ull ka1 = 0ull, ka2 = 0ull;
        ull kb1 = 0ull, kb2 = 0ull;

        for (int r = r0 + wid; r < r0 + RPC; r += 4) {
            int bq = b * Q_ + r;

            const float* row = logits + (size_t)bq * C_;
            float v[4];
            float m = -INFINITY;
#pragma unroll
            for (int i = 0; i < 4; ++i) {
                v[i] = row[lane + 64 * i];
                m = fmaxf(m, v[i]);
            }
#pragma unroll
            for (int off = 32; off >= 1; off >>= 1)
                m = fmaxf(m, __shfl_xor(m, off, 64));

            float e[4];
            float s = 0.0f;
#pragma unroll
            for (int i = 0; i < 4; ++i) {
                e[i] = expf(v[i] - m);
                s += e[i];
            }
#pragma unroll
            for (int off = 32; off >= 1; off >>= 1)
                s += __shfl_xor(s, off, 64);

#pragma unroll
            for (int i = 0; i < 4; ++i)
                s_exp[wid][lane + 64 * i] = e[i];

            const float* pb = pboxes + (size_t)bq * 4;
            float pcx = pb[0], pcy = pb[1], pw = pb[2], ph = pb[3];
            float px1 = pcx - 0.5f * pw, py1 = pcy - 0.5f * ph;
            float px2 = pcx + 0.5f * pw, py2 = pcy + 0.5f * ph;
            float area1 = fmaxf(px2 - px1, 0.0f) * fmaxf(py2 - py1, 0.0f);

            {
                float prob = s_exp[wid][laba] / s;
                float l1 = fabsf(pcx - tcxa) + fabsf(pcy - tcya) + fabsf(pw - twa) + fabsf(ph - tha);
                float iw = fmaxf(fminf(px2, txa2) - fmaxf(px1, txa1), 0.0f);
                float ih = fmaxf(fminf(py2, tya2) - fmaxf(py1, tya1), 0.0f);
                float inter = iw * ih;
                float uni = area1 + area2a - inter;
                float iou = inter / fmaxf(uni, 1e-6f);
                float ew = fmaxf(fmaxf(px2, txa2) - fminf(px1, txa1), 0.0f);
                float eh = fmaxf(fmaxf(py2, tya2) - fminf(py1, tya1), 0.0f);
                float earea = ew * eh;
                float giou = iou - (earea - uni) / fmaxf(earea, 1e-6f);
                float cf = -prob + 5.0f * l1 - 2.0f * giou;
                cost[(size_t)bq * T_ + ta] = cf;
                ull kk = hm_ikey(cf, r, ta);
                if (kk > ka1) { ka2 = ka1; ka1 = kk; }
                else if (kk > ka2) ka2 = kk;
            }
            if (hb) {
                float prob = s_exp[wid][labb] / s;
                float l1 = fabsf(pcx - tcxb) + fabsf(pcy - tcyb) + fabsf(pw - twb) + fabsf(ph - thb_);
                float iw = fmaxf(fminf(px2, txb2) - fmaxf(px1, txb1), 0.0f);
                float ih = fmaxf(fminf(py2, tyb2) - fmaxf(py1, tyb1), 0.0f);
                float inter = iw * ih;
                float uni = area1 + area2b - inter;
                float iou = inter / fmaxf(uni, 1e-6f);
                float ew = fmaxf(fmaxf(px2, txb2) - fminf(px1, txb1), 0.0f);
                float eh = fmaxf(fmaxf(py2, tyb2) - fminf(py1, tyb1), 0.0f);
                float earea = ew * eh;
                float giou = iou - (earea - uni) / fmaxf(earea, 1e-6f);
                float cf = -prob + 5.0f * l1 - 2.0f * giou;
                cost[(size_t)bq * T_ + tb] = cf;
                ull kk = hm_ikey(cf, r, tb);
                if (kk > kb1) { kb2 = kb1; kb1 = kk; }
                else if (kk > kb2) kb2 = kk;
            }
        }

        s_part[wid][lane][0]      = ka1;
        s_part[wid][lane][1]      = ka2;
        s_part[wid][64 + lane][0] = kb1;
        s_part[wid][64 + lane][1] = kb2;
        __syncthreads();
        int tid = threadIdx.x;
        if (tid < T_) {
            ull b1 = 0ull, b2 = 0ull;
#pragma unroll
            for (int w = 0; w < 4; ++w) {
#pragma unroll
                for (int j = 0; j < 2; ++j) {
                    ull cc = s_part[w][tid][j];
                    if (cc > b1) { b2 = b1; b1 = cc; }
                    else if (cc > b2) b2 = cc;
                }
            }
            ull* dst = part + (((size_t)b * CHUNKS + c) * T_ + tid) * 2;
            dst[0] = b1;
            dst[1] = b2;
        }

        // signal completion (canonical producer pattern)
        __syncthreads();
        if (threadIdx.x == 0) {
            __threadfence();
            __hip_atomic_fetch_add(&cnt[b], 1, __ATOMIC_RELEASE,
                                   __HIP_MEMORY_SCOPE_AGENT);
        }
        return;
    }

    // ===================== CONSUMER: greedy for one batch =====================
    if (threadIdx.x >= 64) return;      // one wave per greedy block
    int b = bc - B_ * CHUNKS;
    int l = threadIdx.x;                // 0..63
    const float* Cb = cost + (size_t)b * Q_ * T_;

    // spin until this batch's 25 producer blocks have signaled
    while (__hip_atomic_load(&cnt[b], __ATOMIC_ACQUIRE,
                             __HIP_MEMORY_SCOPE_AGENT) < CHUNKS) {
        __builtin_amdgcn_s_sleep(2);
    }
    __threadfence();

    int  t0 = l, t1 = 64 + l;
    bool a1 = (t1 < T_);

    // ---- phase 0: fold chunk top-2 partials (u64), split to 32-bit ----
    ull c1a = 0ull, c2a = 0ull, c1b = 0ull, c2b = 0ull;
#pragma unroll
    for (int c = 0; c < CHUNKS; ++c) {
        const ull* p0 = part + (((size_t)b * CHUNKS + c) * T_ + t0) * 2;
#pragma unroll
        for (int j = 0; j < 2; ++j) {
            ull cc = p0[j];
            if (cc > c1a) { c2a = c1a; c1a = cc; }
            else if (cc > c2a) c2a = cc;
        }
        if (a1) {
            const ull* p1 = part + (((size_t)b * CHUNKS + c) * T_ + t1) * 2;
#pragma unroll
            for (int j = 0; j < 2; ++j) {
                ull cc = p1[j];
                if (cc > c1b) { c2b = c1b; c1b = cc; }
                else if (cc > c2b) c2b = cc;
            }
        }
    }
    // split: key = ~ikey; v = key>>18, id = key & 0x3FFFF
    u32 va  = (u32)((~c1a) >> 18), ida  = (u32)(~c1a) & 0x3FFFFu;
    u32 v2a = (u32)((~c2a) >> 18), id2a = (u32)(~c2a) & 0x3FFFFu;
    u32 vb  = a1 ? (u32)((~c1b) >> 18) : 0xFFFFFFFFu;
    u32 idb = a1 ? ((u32)(~c1b) & 0x3FFFFu) : 0x3FFFFu;
    u32 v2b = a1 ? (u32)((~c2b) >> 18) : 0xFFFFFFFFu;
    u32 id2b = a1 ? ((u32)(~c2b) & 0x3FFFFu) : 0x3FFFFu;

    unsigned removed = 0u;              // bit i => row (l + 64*i) removed
    u32 pk0 = 0u, pk1 = 0u;             // pick registers: lane k&63 holds pick k

    int k = 0;
    while (k < N_) {
        // ---- phase 1: wave-min of value (as max of ~v)
        u32 ya = ~va, yb = ~vb;
        u32 winy = hm_wave_max_u32_full(ya > yb ? ya : yb);

        // ---- phase 2: wave-min of id among value-ties (as max of ~id)
        u32 za = (ya == winy) ? ~ida : 0u;
        u32 zb = (yb == winy) ? ~idb : 0u;
        u32 winz = hm_wave_max_u32_full(za > zb ? za : zb);
        u32 winid = (~winz) & 0x3FFFFu;

        int t = (int)(winid & 127u);
        int q = (int)((winid >> 7) & 1023u);

        if (winid & 0x20000u) {
            // ---- RARE: stale lower-bound won -> rescan column t, retry k
            ull b1 = 0ull, b2 = 0ull;
#pragma unroll
            for (int i = 0; i < ROWS_PER_LANE; ++i) {
                int r = l + 64 * i;
                bool ok = (r < Q_) && !((removed >> i) & 1u);
                float v = ok ? Cb[(size_t)r * T_ + t] : BIGF;
                ull ik = ok ? hm_ikey(v, r, t) : 0ull;
                if (ik > b1) { b2 = b1; b1 = ik; }
                else if (ik > b2) b2 = ik;
            }
            ull w1 = hm_wave_max_full64(b1);
            ull alt = (b1 == w1) ? b2 : b1;   // keys unique
            ull w2 = hm_wave_max_full64(alt);
            if (t0 == t) {
                va  = (u32)((~w1) >> 18); ida  = (u32)(~w1) & 0x3FFFFu;
                v2a = (u32)((~w2) >> 18); id2a = (u32)(~w2) & 0x3FFFFu;
            }
            if (t1 == t) {
                vb  = (u32)((~w1) >> 18); idb  = (u32)(~w1) & 0x3FFFFu;
                v2b = (u32)((~w2) >> 18); id2b = (u32)(~w2) & 0x3FFFFu;
            }
            continue;
        }

        // ---- accept pick into registers (lane k&63)
        u32 qt = winid & 0x1FFFFu;
        if (k < 64) { if (l == k)        pk0 = qt; }
        else        { if (l == (k & 63)) pk1 = qt; }
        if ((q & 63) == l) removed |= 1u << (q >> 6);

        // ---- branch-free top-2 maintenance (all 32-bit), column a
        {
            bool die1 = (((ida  >> 7) & 1023u) == (u32)q);
            bool die2 = (((id2a >> 7) & 1023u) == (u32)q);
            u32 nva  = die1 ? v2a  : va;
            u32 nida = die1 ? id2a : ida;
            u32 nid2 = (die1 || die2) ? (id2a | 0x20000u) : id2a;
            bool kill = (t0 == t);
            va   = kill ? 0xFFFFFFFFu : nva;
            ida  = kill ? 0x3FFFFu    : nida;
            v2a  = kill ? 0xFFFFFFFFu : v2a;
            id2a = kill ? 0x3FFFFu    : nid2;
        }
        // ---- column b
        {
            bool die1 = (((idb  >> 7) & 1023u) == (u32)q);
            bool die2 = (((id2b >> 7) & 1023u) == (u32)q);
            u32 nvb  = die1 ? v2b  : vb;
            u32 nidb = die1 ? id2b : idb;
            u32 nid2 = (die1 || die2) ? (id2b | 0x20000u) : id2b;
            bool kill = (t1 == t);
            vb   = kill ? 0xFFFFFFFFu : nvb;
            idb  = kill ? 0x3FFFFu    : nidb;
            v2b  = kill ? 0xFFFFFFFFu : v2b;
            id2b = kill ? 0x3FFFFu    : nid2;
        }

        ++k;
    }

    // ---- coalesced final store of all picks
    float* os = out_src + b * N_;
    float* ot = out_tgt + b * N_;
    os[l] = (float)(pk0 >> 7);
    ot[l] = (float)(pk0 & 127u);
    if (l < N_ - 64) {
        os[64 + l] = (float)(pk1 >> 7);
        ot[64 + l] = (float)(pk1 & 127u);
    }
}

// ---------------------------------------------------------------------------
extern "C" void kernel_launch(void* const* d_in, const int* in_sizes, int n_in,
                              void* d_out, int out_size, void* d_ws, size_t ws_size,
                              hipStream_t stream)
{
    const float* pred_logits = (const float*)d_in[0];  // [B,Q,C]
    const float* pred_boxes  = (const float*)d_in[1];  // [B,Q,4]
    const int*   tgt_labels  = (const int*)d_in[2];    // [B,T]
    const float* tgt_boxes   = (const float*)d_in[3];  // [B,T,4]

    float* out_cost = (float*)d_out;                       // [B,Q,T]
    float* out_src  = out_cost + (size_t)B_ * Q_ * T_;     // [B,N]
    float* out_tgt  = out_src  + (size_t)B_ * N_;          // [B,N]

    ull* part = (ull*)d_ws;                                // [B,CHUNKS,T,2] 2.56 MB
    int* cnt  = (int*)(part + (size_t)B_ * CHUNKS * T_ * 2); // [B]

    // 1: zero completion counters (replay-safe)
    hm_zero<<<1, 64, 0, stream>>>(cnt);

    // 2: fused producers (cost+colmin) + consumers (greedy, spin-wait)
    hm_fused<<<B_ * CHUNKS + B_, 256, 0, stream>>>(
        pred_logits, pred_boxes, tgt_labels, tgt_boxes,
        out_cost, part, cnt, out_src, out_tgt);
}

// Round 21
// 90.071 us; speedup vs baseline: 1.9534x; 1.9534x over previous
//
#include <hip/hip_runtime.h>
#include <math.h>

#define B_ 64
#define Q_ 900
#define C_ 256
#define T_ 100
#define N_ 100            // min(Q,T)
#define BIGF 1.0e30f
#define ROWS_PER_LANE 15  // ceil(900/64) — rescan striding
#define CHUNKS 25         // row-chunks for colmin partials
#define RPC 36            // rows per chunk

typedef unsigned int u32;
typedef unsigned long long ull;

// ---------------------------------------------------------------------------
// Key scheme:
//   u64 key  = ordf(v)<<18 | stale<<17 | row<<7 | t   (partials / rescan)
//   ikey = ~key (max semantics, identity 0)
// Greedy holds 32-bit split state: v = ordf(val), id = stale<<17|row<<7|t.
// Pick order = lex(value, stale, row, t) == jnp.argmin flat order for fresh.
// ---------------------------------------------------------------------------
__device__ inline u32 hm_ordf(float v) {
    u32 u = __float_as_uint(v);
    return (u & 0x80000000u) ? ~u : (u | 0x80000000u);
}
__device__ inline ull hm_ikey(float v, int r, int t) {
    return ~(((ull)hm_ordf(v) << 18) | ((ull)(u32)r << 7) | (ull)(u32)t);
}

// ---------------------------------------------------------------------------
// f32 DPP reduction helpers (VALU pipe; replaces ds_bpermute-based __shfl_xor
// whose 12 serial ~40cy LDS-pipe hops were the cost kernel's 45% stall).
// max: old = -inf (exact; max is order-independent -> m bit-identical).
// sum: old = 0 (association order differs from the old XOR butterfly by
// ~1 ulp on s — far below the measured pick-gap scale).
// Chain: row_shr 1/2/4/8 + row_bcast15/31 -> lane 63 -> readlane (SGPR).
// ---------------------------------------------------------------------------
template <int CTRL>
__device__ inline float hm_dppmax_f(float x) {
    int p = __builtin_amdgcn_update_dpp((int)0xFF800000, __float_as_int(x),
                                        CTRL, 0xF, 0xF, false);
    return fmaxf(x, __int_as_float(p));
}
template <int CTRL>
__device__ inline float hm_dppadd_f(float x) {
    int p = __builtin_amdgcn_update_dpp(0, __float_as_int(x),
                                        CTRL, 0xF, 0xF, false);
    return x + __int_as_float(p);
}
__device__ inline float hm_wave_max_f(float x) {
    x = hm_dppmax_f<0x111>(x);
    x = hm_dppmax_f<0x112>(x);
    x = hm_dppmax_f<0x114>(x);
    x = hm_dppmax_f<0x118>(x);
    x = hm_dppmax_f<0x142>(x);
    x = hm_dppmax_f<0x143>(x);
    return __int_as_float(__builtin_amdgcn_readlane(__float_as_int(x), 63));
}
__device__ inline float hm_wave_sum_f(float x) {
    x = hm_dppadd_f<0x111>(x);
    x = hm_dppadd_f<0x112>(x);
    x = hm_dppadd_f<0x114>(x);
    x = hm_dppadd_f<0x118>(x);
    x = hm_dppadd_f<0x142>(x);
    x = hm_dppadd_f<0x143>(x);
    return __int_as_float(__builtin_amdgcn_readlane(__float_as_int(x), 63));
}

// ---------------------------------------------------------------------------
// Fused cost + column TOP-2 partials — f32 math mirroring the reference
// (R16/R18 body; only the two wave reductions swapped to DPP chains).
// ---------------------------------------------------------------------------
__global__ __launch_bounds__(256) void hm_cost_colmin_f32(
    const float* __restrict__ logits,   // [B,Q,C]
    const float* __restrict__ pboxes,   // [B,Q,4] cxcywh
    const int*   __restrict__ tlabels,  // [B,T]
    const float* __restrict__ tboxes,   // [B,T,4] cxcywh
    float* __restrict__ cost,           // [B,Q,T]
    ull* __restrict__ part)             // [B,CHUNKS,T,2] inverted top-2 keys
{
    int bc   = blockIdx.x;
    int b    = bc / CHUNKS;
    int c    = bc % CHUNKS;
    int lane = threadIdx.x & 63;
    int wid  = threadIdx.x >> 6;        // 0..3
    int r0   = c * RPC;

    __shared__ float s_exp[4][C_];      // 4 KB
    __shared__ ull   s_part[4][128][2]; // 8 KB

    int ta = lane, tb = 64 + lane;
    bool hb = (tb < T_);
    int laba = tlabels[b * T_ + ta];
    int labb = hb ? tlabels[b * T_ + tb] : 0;
    const float* tba = tboxes + ((size_t)b * T_ + ta) * 4;
    const float* tbb = tboxes + ((size_t)b * T_ + (hb ? tb : 0)) * 4;
    float tcxa = tba[0], tcya = tba[1], twa = tba[2], tha = tba[3];
    float tcxb = tbb[0], tcyb = tbb[1], twb = tbb[2], thb_ = tbb[3];
    float txa1 = tcxa - 0.5f * twa, tya1 = tcya - 0.5f * tha;
    float txa2 = tcxa + 0.5f * twa, tya2 = tcya + 0.5f * tha;
    float txb1 = tcxb - 0.5f * twb, tyb1 = tcyb - 0.5f * thb_;
    float txb2 = tcxb + 0.5f * twb, tyb2 = tcyb + 0.5f * thb_;
    float area2a = fmaxf(txa2 - txa1, 0.0f) * fmaxf(tya2 - tya1, 0.0f);
    float area2b = fmaxf(txb2 - txb1, 0.0f) * fmaxf(tyb2 - tyb1, 0.0f);

    ull ka1 = 0ull, ka2 = 0ull;
    ull kb1 = 0ull, kb2 = 0ull;

    for (int r = r0 + wid; r < r0 + RPC; r += 4) {
        int bq = b * Q_ + r;

        const float* row = logits + (size_t)bq * C_;
        float v[4];
        float ml = -INFINITY;
#pragma unroll
        for (int i = 0; i < 4; ++i) {
            v[i] = row[lane + 64 * i];
            ml = fmaxf(ml, v[i]);
        }
        float m = hm_wave_max_f(ml);    // exact (max order-independent)

        float e[4];
        float sl = 0.0f;
#pragma unroll
        for (int i = 0; i < 4; ++i) {
            e[i] = expf(v[i] - m);
            sl += e[i];
        }
        float s = hm_wave_sum_f(sl);    // ~1ulp association change vs butterfly

#pragma unroll
        for (int i = 0; i < 4; ++i)
            s_exp[wid][lane + 64 * i] = e[i];

        const float* pb = pboxes + (size_t)bq * 4;
        float pcx = pb[0], pcy = pb[1], pw = pb[2], ph = pb[3];
        float px1 = pcx - 0.5f * pw, py1 = pcy - 0.5f * ph;
        float px2 = pcx + 0.5f * pw, py2 = pcy + 0.5f * ph;
        float area1 = fmaxf(px2 - px1, 0.0f) * fmaxf(py2 - py1, 0.0f);

        {
            float prob = s_exp[wid][laba] / s;
            float l1 = fabsf(pcx - tcxa) + fabsf(pcy - tcya) + fabsf(pw - twa) + fabsf(ph - tha);
            float iw = fmaxf(fminf(px2, txa2) - fmaxf(px1, txa1), 0.0f);
            float ih = fmaxf(fminf(py2, tya2) - fmaxf(py1, tya1), 0.0f);
            float inter = iw * ih;
            float uni = area1 + area2a - inter;
            float iou = inter / fmaxf(uni, 1e-6f);
            float ew = fmaxf(fmaxf(px2, txa2) - fminf(px1, txa1), 0.0f);
            float eh = fmaxf(fmaxf(py2, tya2) - fminf(py1, tya1), 0.0f);
            float earea = ew * eh;
            float giou = iou - (earea - uni) / fmaxf(earea, 1e-6f);
            float cf = -prob + 5.0f * l1 - 2.0f * giou;
            cost[(size_t)bq * T_ + ta] = cf;
            ull kk = hm_ikey(cf, r, ta);
            if (kk > ka1) { ka2 = ka1; ka1 = kk; }
            else if (kk > ka2) ka2 = kk;
        }
        if (hb) {
            float prob = s_exp[wid][labb] / s;
            float l1 = fabsf(pcx - tcxb) + fabsf(pcy - tcyb) + fabsf(pw - twb) + fabsf(ph - thb_);
            float iw = fmaxf(fminf(px2, txb2) - fmaxf(px1, txb1), 0.0f);
            float ih = fmaxf(fminf(py2, tyb2) - fmaxf(py1, tyb1), 0.0f);
            float inter = iw * ih;
            float uni = area1 + area2b - inter;
            float iou = inter / fmaxf(uni, 1e-6f);
            float ew = fmaxf(fmaxf(px2, txb2) - fminf(px1, txb1), 0.0f);
            float eh = fmaxf(fmaxf(py2, tyb2) - fminf(py1, tyb1), 0.0f);
            float earea = ew * eh;
            float giou = iou - (earea - uni) / fmaxf(earea, 1e-6f);
            float cf = -prob + 5.0f * l1 - 2.0f * giou;
            cost[(size_t)bq * T_ + tb] = cf;
            ull kk = hm_ikey(cf, r, tb);
            if (kk > kb1) { kb2 = kb1; kb1 = kk; }
            else if (kk > kb2) kb2 = kk;
        }
    }

    s_part[wid][lane][0]      = ka1;
    s_part[wid][lane][1]      = ka2;
    s_part[wid][64 + lane][0] = kb1;
    s_part[wid][64 + lane][1] = kb2;
    __syncthreads();
    int tid = threadIdx.x;
    if (tid < T_) {
        ull b1 = 0ull, b2 = 0ull;
#pragma unroll
        for (int w = 0; w < 4; ++w) {
#pragma unroll
            for (int j = 0; j < 2; ++j) {
                ull cc = s_part[w][tid][j];
                if (cc > b1) { b2 = b1; b1 = cc; }
                else if (cc > b2) b2 = cc;
            }
        }
        ull* dst = part + (((size_t)b * CHUNKS + c) * T_ + tid) * 2;
        dst[0] = b1;
        dst[1] = b2;
    }
}

// ---------------------------------------------------------------------------
// DPP helpers (greedy).
// ---------------------------------------------------------------------------
__device__ inline u32 hm_umax32(u32 a, u32 b) { return a > b ? a : b; }

__device__ inline u32 hm_wave_max_u32_full(u32 y) {
    y = hm_umax32(y, (u32)__builtin_amdgcn_update_dpp(0, (int)y, 0x111, 0xF, 0xF, false));
    y = hm_umax32(y, (u32)__builtin_amdgcn_update_dpp(0, (int)y, 0x112, 0xF, 0xF, false));
    y = hm_umax32(y, (u32)__builtin_amdgcn_update_dpp(0, (int)y, 0x114, 0xF, 0xF, false));
    y = hm_umax32(y, (u32)__builtin_amdgcn_update_dpp(0, (int)y, 0x118, 0xF, 0xF, false));
    y = hm_umax32(y, (u32)__builtin_amdgcn_update_dpp(0, (int)y, 0x142, 0xF, 0xF, false));
    y = hm_umax32(y, (u32)__builtin_amdgcn_update_dpp(0, (int)y, 0x143, 0xF, 0xF, false));
    return (u32)__builtin_amdgcn_readlane((int)y, 63);
}

template <int CTRL>
__device__ inline ull hm_dpp64(ull x) {
    u32 lo = (u32)x, hi = (u32)(x >> 32);
    lo = (u32)__builtin_amdgcn_update_dpp(0, (int)lo, CTRL, 0xF, 0xF, false);
    hi = (u32)__builtin_amdgcn_update_dpp(0, (int)hi, CTRL, 0xF, 0xF, false);
    return ((ull)hi << 32) | lo;
}
__device__ inline ull hm_wave_max_full64(ull x) {     // rare rescan path only
    ull p;
    p = hm_dpp64<0x111>(x); x = (p > x) ? p : x;
    p = hm_dpp64<0x112>(x); x = (p > x) ? p : x;
    p = hm_dpp64<0x114>(x); x = (p > x) ? p : x;
    p = hm_dpp64<0x118>(x); x = (p > x) ? p : x;
    p = hm_dpp64<0x142>(x); x = (p > x) ? p : x;
    p = hm_dpp64<0x143>(x); x = (p > x) ? p : x;
    u32 lo = (u32)__builtin_amdgcn_readlane((int)(u32)x, 63);
    u32 hi = (u32)__builtin_amdgcn_readlane((int)(u32)(x >> 32), 63);
    return ((ull)hi << 32) | lo;
}

// ---------------------------------------------------------------------------
// Greedy: ONE WAVE per batch — R18's measured-best body, VERBATIM.
// ---------------------------------------------------------------------------
__global__ __launch_bounds__(64) void hm_greedy_32(
    const float* __restrict__ cost,     // [B,Q,T]
    const ull* __restrict__ part,       // [B,CHUNKS,T,2]
    float* __restrict__ out_src,        // [B,N]
    float* __restrict__ out_tgt)        // [B,N]
{
    int b = blockIdx.x;
    int l = threadIdx.x;                // 0..63
    const float* Cb = cost + (size_t)b * Q_ * T_;

    int  t0 = l, t1 = 64 + l;
    bool a1 = (t1 < T_);

    // ---- phase 0: fold chunk top-2 partials (u64), split to 32-bit ----
    ull c1a = 0ull, c2a = 0ull, c1b = 0ull, c2b = 0ull;
#pragma unroll
    for (int c = 0; c < CHUNKS; ++c) {
        const ull* p0 = part + (((size_t)b * CHUNKS + c) * T_ + t0) * 2;
#pragma unroll
        for (int j = 0; j < 2; ++j) {
            ull cc = p0[j];
            if (cc > c1a) { c2a = c1a; c1a = cc; }
            else if (cc > c2a) c2a = cc;
        }
        if (a1) {
            const ull* p1 = part + (((size_t)b * CHUNKS + c) * T_ + t1) * 2;
#pragma unroll
            for (int j = 0; j < 2; ++j) {
                ull cc = p1[j];
                if (cc > c1b) { c2b = c1b; c1b = cc; }
                else if (cc > c2b) c2b = cc;
            }
        }
    }
    // split: key = ~ikey; v = key>>18, id = key & 0x3FFFF
    u32 va  = (u32)((~c1a) >> 18), ida  = (u32)(~c1a) & 0x3FFFFu;
    u32 v2a = (u32)((~c2a) >> 18), id2a = (u32)(~c2a) & 0x3FFFFu;
    u32 vb  = a1 ? (u32)((~c1b) >> 18) : 0xFFFFFFFFu;
    u32 idb = a1 ? ((u32)(~c1b) & 0x3FFFFu) : 0x3FFFFu;
    u32 v2b = a1 ? (u32)((~c2b) >> 18) : 0xFFFFFFFFu;
    u32 id2b = a1 ? ((u32)(~c2b) & 0x3FFFFu) : 0x3FFFFu;

    unsigned removed = 0u;              // bit i => row (l + 64*i) removed
    u32 pk0 = 0u, pk1 = 0u;             // pick registers: lane k&63 holds pick k

    int k = 0;
    while (k < N_) {
        // ---- phase 1: wave-min of value (as max of ~v)
        u32 ya = ~va, yb = ~vb;
        u32 winy = hm_wave_max_u32_full(ya > yb ? ya : yb);

        // ---- phase 2: wave-min of id among value-ties (as max of ~id)
        u32 za = (ya == winy) ? ~ida : 0u;
        u32 zb = (yb == winy) ? ~idb : 0u;
        u32 winz = hm_wave_max_u32_full(za > zb ? za : zb);
        u32 winid = (~winz) & 0x3FFFFu;

        int t = (int)(winid & 127u);
        int q = (int)((winid >> 7) & 1023u);

        if (winid & 0x20000u) {
            // ---- RARE: stale lower-bound won -> rescan column t, retry k
            ull b1 = 0ull, b2 = 0ull;
#pragma unroll
            for (int i = 0; i < ROWS_PER_LANE; ++i) {
                int r = l + 64 * i;
                bool ok = (r < Q_) && !((removed >> i) & 1u);
                float v = ok ? Cb[(size_t)r * T_ + t] : BIGF;
                ull ik = ok ? hm_ikey(v, r, t) : 0ull;
                if (ik > b1) { b2 = b1; b1 = ik; }
                else if (ik > b2) b2 = ik;
            }
            ull w1 = hm_wave_max_full64(b1);
            ull alt = (b1 == w1) ? b2 : b1;   // keys unique
            ull w2 = hm_wave_max_full64(alt);
            if (t0 == t) {
                va  = (u32)((~w1) >> 18); ida  = (u32)(~w1) & 0x3FFFFu;
                v2a = (u32)((~w2) >> 18); id2a = (u32)(~w2) & 0x3FFFFu;
            }
            if (t1 == t) {
                vb  = (u32)((~w1) >> 18); idb  = (u32)(~w1) & 0x3FFFFu;
                v2b = (u32)((~w2) >> 18); id2b = (u32)(~w2) & 0x3FFFFu;
            }
            continue;
        }

        // ---- accept pick into registers (lane k&63)
        u32 qt = winid & 0x1FFFFu;
        if (k < 64) { if (l == k)        pk0 = qt; }
        else        { if (l == (k & 63)) pk1 = qt; }
        if ((q & 63) == l) removed |= 1u << (q >> 6);

        // ---- branch-free top-2 maintenance (all 32-bit), column a
        {
            bool die1 = (((ida  >> 7) & 1023u) == (u32)q);
            bool die2 = (((id2a >> 7) & 1023u) == (u32)q);
            u32 nva  = die1 ? v2a  : va;
            u32 nida = die1 ? id2a : ida;
            u32 nid2 = (die1 || die2) ? (id2a | 0x20000u) : id2a;
            bool kill = (t0 == t);
            va   = kill ? 0xFFFFFFFFu : nva;
            ida  = kill ? 0x3FFFFu    : nida;
            v2a  = kill ? 0xFFFFFFFFu : v2a;
            id2a = kill ? 0x3FFFFu    : nid2;
        }
        // ---- column b
        {
            bool die1 = (((idb  >> 7) & 1023u) == (u32)q);
            bool die2 = (((id2b >> 7) & 1023u) == (u32)q);
            u32 nvb  = die1 ? v2b  : vb;
            u32 nidb = die1 ? id2b : idb;
            u32 nid2 = (die1 || die2) ? (id2b | 0x20000u) : id2b;
            bool kill = (t1 == t);
            vb   = kill ? 0xFFFFFFFFu : nvb;
            idb  = kill ? 0x3FFFFu    : nidb;
            v2b  = kill ? 0xFFFFFFFFu : v2b;
            id2b = kill ? 0x3FFFFu    : nid2;
        }

        ++k;
    }

    // ---- coalesced final store of all picks
    float* os = out_src + b * N_;
    float* ot = out_tgt + b * N_;
    os[l] = (float)(pk0 >> 7);
    ot[l] = (float)(pk0 & 127u);
    if (l < N_ - 64) {
        os[64 + l] = (float)(pk1 >> 7);
        ot[64 + l] = (float)(pk1 & 127u);
    }
}

// ---------------------------------------------------------------------------
extern "C" void kernel_launch(void* const* d_in, const int* in_sizes, int n_in,
                              void* d_out, int out_size, void* d_ws, size_t ws_size,
                              hipStream_t stream)
{
    const float* pred_logits = (const float*)d_in[0];  // [B,Q,C]
    const float* pred_boxes  = (const float*)d_in[1];  // [B,Q,4]
    const int*   tgt_labels  = (const int*)d_in[2];    // [B,T]
    const float* tgt_boxes   = (const float*)d_in[3];  // [B,T,4]

    float* out_cost = (float*)d_out;                       // [B,Q,T]
    float* out_src  = out_cost + (size_t)B_ * Q_ * T_;     // [B,N]
    float* out_tgt  = out_src  + (size_t)B_ * N_;          // [B,N]

    ull* part = (ull*)d_ws;                                // [B,CHUNKS,T,2] 2.56 MB

    // 1: fused softmax + cost + column top-2 partials — f32, DPP reductions
    hm_cost_colmin_f32<<<B_ * CHUNKS, 256, 0, stream>>>(pred_logits, pred_boxes,
                                                        tgt_labels, tgt_boxes,
                                                        out_cost, part);

    // 2: greedy — one wave per batch, R18 two-phase DPP rounds (best measured)
    hm_greedy_32<<<B_, 64, 0, stream>>>(out_cost, part, out_src, out_tgt);
}